// Round 1
// baseline (978.628 us; speedup 1.0000x reference)
//
#include <hip/hip_runtime.h>

#define EPS 1e-12f
#define NSCAN 256   // scan blocks/threads

// ---------------------------------------------------------------------------
// Pipeline: zero cursor -> count -> scan(3 kernels) -> fill(int2 CSR, atomicSub)
//           -> gather (batch PINNED to XCD: per-XCD L2 holds exactly one
//              batch's 2.4MB vertex array; CSR/out streamed non-temporally)
// CSR entry at corner v of face (i0,i1,i2) stores the other two indices (a,b)
// in cyclic order; contribution = (A - v) x (B - v), which equals the
// reference's cross(v2-v1, v0-v1) for every corner (cyclic identity).
// ---------------------------------------------------------------------------

__global__ void zero_ints(int* __restrict__ p, int n) {
    int i = blockIdx.x * blockDim.x + threadIdx.x;
    if (i < n) p[i] = 0;
}

__global__ void count_kernel(const int* __restrict__ faces, int* __restrict__ counts, int F) {
    int f = blockIdx.x * blockDim.x + threadIdx.x;
    if (f >= F) return;
    atomicAdd(&counts[faces[3 * f + 0]], 1);
    atomicAdd(&counts[faces[3 * f + 1]], 1);
    atomicAdd(&counts[faces[3 * f + 2]], 1);
}

// --- 3-phase exclusive scan of counts[V] -> offsets[V+1] ---

__global__ __launch_bounds__(NSCAN) void scan_partials(const int* __restrict__ counts,
                                                       int* __restrict__ partials,
                                                       int V, int chunk) {
    int b = blockIdx.x, t = threadIdx.x;
    int bstart = b * chunk;
    int bend = min(bstart + chunk, V);
    int s = 0;
    for (int i = bstart + t; i < bend; i += NSCAN) s += counts[i];
    __shared__ int red[NSCAN];
    red[t] = s;
    __syncthreads();
    for (int o = NSCAN / 2; o > 0; o >>= 1) {
        if (t < o) red[t] += red[t + o];
        __syncthreads();
    }
    if (t == 0) partials[b] = red[0];
}

__global__ __launch_bounds__(NSCAN) void scan_top(int* __restrict__ partials) {
    __shared__ int s[NSCAN];
    int t = threadIdx.x;
    int v = partials[t];
    s[t] = v;
    __syncthreads();
    for (int o = 1; o < NSCAN; o <<= 1) {
        int u = (t >= o) ? s[t - o] : 0;
        __syncthreads();
        s[t] += u;
        __syncthreads();
    }
    partials[t] = s[t] - v;  // exclusive
}

__global__ __launch_bounds__(NSCAN) void scan_final(const int* __restrict__ counts,
                                                    const int* __restrict__ partials,
                                                    int* __restrict__ offsets,
                                                    int V, int chunk) {
    int b = blockIdx.x, t = threadIdx.x;
    int bstart = b * chunk;
    int bend = min(bstart + chunk, V);
    int sc = (chunk + NSCAN - 1) / NSCAN;
    int tstart = bstart + t * sc;
    int tend = min(tstart + sc, bend);
    int c[8];
    int n = 0, tsum = 0;
    for (int i = tstart; i < tend; i++) {
        int cv = counts[i];
        c[n++] = cv;
        tsum += cv;
    }
    __shared__ int s[NSCAN];
    s[t] = tsum;
    __syncthreads();
    for (int o = 1; o < NSCAN; o <<= 1) {
        int u = (t >= o) ? s[t - o] : 0;
        __syncthreads();
        s[t] += u;
        __syncthreads();
    }
    int run = partials[b] + s[t] - tsum;  // exclusive base for this thread
    n = 0;
    for (int i = tstart; i < tend; i++) {
        offsets[i] = run;
        run += c[n++];
    }
    if (bend == V && tend == V) offsets[V] = run;  // last block; benign same-value race
}

// fill: cursor still holds counts; atomicSub gives unique slot without re-zero
__global__ void fill_kernel(const int* __restrict__ faces,
                            const int* __restrict__ offsets,
                            int* __restrict__ cursor,
                            int2* __restrict__ csr, int F) {
    int f = blockIdx.x * blockDim.x + threadIdx.x;
    if (f >= F) return;
    int i0 = faces[3 * f + 0];
    int i1 = faces[3 * f + 1];
    int i2 = faces[3 * f + 2];
    int vs[3] = {i0, i1, i2};
    int as[3] = {i1, i2, i0};
    int bs[3] = {i2, i0, i1};
#pragma unroll
    for (int c = 0; c < 3; c++) {
        int v = vs[c];
        int old = atomicSub(&cursor[v], 1);
        int pos = offsets[v] + old - 1;
        csr[pos] = make_int2(as[c], bs[c]);
    }
}

// Batch-pinned gather: XCD k (== blockIdx&7 under round-robin dispatch)
// processes batches k, k+8, k+16, ... sequentially. Working set per XCD L2
// = one batch's verts (2.4 MB < 4 MiB). CSR is re-streamed per batch but is
// L3-resident; loaded non-temporally so it doesn't evict verts from L2.
// Output stores are non-temporal (never re-read).
__global__ __launch_bounds__(256) void gather_kernel(const float* __restrict__ verts,
                                                     const int* __restrict__ offsets,
                                                     const int2* __restrict__ csr,
                                                     float* __restrict__ out,
                                                     int V, int B, int vpb) {
    int i = blockIdx.x;
    int xcd = i & 7;
    int j = i >> 3;
    int lb = j / vpb;            // local batch index on this XCD
    int vblk = j - lb * vpb;
    int batch = lb * 8 + xcd;
    if (batch >= B) return;
    int v = vblk * 256 + threadIdx.x;
    if (v >= V) return;

    const float* vb = verts + (size_t)batch * V * 3;
    float vx = vb[3 * v + 0], vy = vb[3 * v + 1], vz = vb[3 * v + 2];

    int s = offsets[v];
    int e = offsets[v + 1];
    float ax = 0.f, ay = 0.f, az = 0.f;
    for (int k = s; k < e; k++) {
        unsigned long long pr =
            __builtin_nontemporal_load((const unsigned long long*)(csr + k));
        int pa = (int)(unsigned int)(pr & 0xffffffffull);
        int pb = (int)(unsigned int)(pr >> 32);
        const float* A = vb + 3 * (size_t)pa;
        const float* Bv = vb + 3 * (size_t)pb;
        float aX = A[0] - vx, aY = A[1] - vy, aZ = A[2] - vz;
        float bX = Bv[0] - vx, bY = Bv[1] - vy, bZ = Bv[2] - vz;
        ax += aY * bZ - aZ * bY;
        ay += aZ * bX - aX * bZ;
        az += aX * bY - aY * bX;
    }
    float sc = rsqrtf(fmaxf(ax * ax + ay * ay + az * az, EPS));
    size_t o = ((size_t)batch * V + v) * 3;
    __builtin_nontemporal_store(ax * sc, out + o + 0);
    __builtin_nontemporal_store(ay * sc, out + o + 1);
    __builtin_nontemporal_store(az * sc, out + o + 2);
}

extern "C" void kernel_launch(void* const* d_in, const int* in_sizes, int n_in,
                              void* d_out, int out_size, void* d_ws, size_t ws_size,
                              hipStream_t stream) {
    const float* verts = (const float*)d_in[0];
    const int* faces = (const int*)d_in[1];
    float* out = (float*)d_out;

    const int V = 200000;
    const int F = in_sizes[1] / 3;           // 400000
    const int B = in_sizes[0] / (3 * V);     // 32
    const int E = 3 * F;                     // 1.2M csr entries

    // workspace layout: offsets[V+1] | cursor[V] | partials[NSCAN] | csr[E] (int2)
    int* offsets = (int*)d_ws;
    int* cursor = offsets + (V + 1);
    int* partials = cursor + V;
    int2* csr = (int2*)(partials + NSCAN);

    const int chunk = (V + NSCAN - 1) / NSCAN;  // 782

    zero_ints<<<(V + 255) / 256, 256, 0, stream>>>(cursor, V);
    count_kernel<<<(F + 255) / 256, 256, 0, stream>>>(faces, cursor, F);
    scan_partials<<<NSCAN, NSCAN, 0, stream>>>(cursor, partials, V, chunk);
    scan_top<<<1, NSCAN, 0, stream>>>(partials);
    scan_final<<<NSCAN, NSCAN, 0, stream>>>(cursor, partials, offsets, V, chunk);
    fill_kernel<<<(F + 255) / 256, 256, 0, stream>>>(faces, offsets, cursor, csr, F);

    int vpb = (V + 255) / 256;               // 782 vertex-blocks per batch
    int bpx = (B + 7) / 8;                   // 4 batches per XCD
    int nblk = 8 * bpx * vpb;                // 25024
    gather_kernel<<<nblk, 256, 0, stream>>>(verts, offsets, csr, out, V, B, vpb);
}